// Round 4
// baseline (567.451 us; speedup 1.0000x reference)
//
#include <hip/hip_runtime.h>

#define N_NODES 100000
#define N_EDGES 1600000
#define IN_F    128
#define HID_F   256
#define OUT_F   160
#define BN_EPS  1e-5f

typedef __attribute__((ext_vector_type(8))) short bf16x8;
typedef __attribute__((ext_vector_type(4))) float f32x4;

static __device__ inline unsigned short f2bf(float x) {
  unsigned u = __float_as_uint(x);
  return (unsigned short)((u + 0x7fffu + ((u >> 16) & 1u)) >> 16);
}
static __device__ inline unsigned f2bf_pair(float lo, float hi) {
  return (unsigned)f2bf(lo) | ((unsigned)f2bf(hi) << 16);
}

// ---------------------------------------------------------------------------
// K0: histogram of dst into cursor (pre-zeroed)
// ---------------------------------------------------------------------------
__global__ __launch_bounds__(256) void k_hist(const int* __restrict__ dst,
                                              int* __restrict__ cursor) {
  int e = blockIdx.x * 256 + threadIdx.x;
  if (e < N_EDGES) atomicAdd(&cursor[dst[e]], 1);
}

// ---------------------------------------------------------------------------
// K1: single-block exclusive scan (validated round 2)
// ---------------------------------------------------------------------------
__global__ __launch_bounds__(1024) void k_scan(int* __restrict__ cursor,
                                               int* __restrict__ offs) {
  __shared__ int wsum[16];
  __shared__ int chunk_total;
  __shared__ int carry;
  const int tid = threadIdx.x;
  const int lane = tid & 63, wid = tid >> 6;
  if (tid == 0) carry = 0;
  __syncthreads();
  for (int base = 0; base < N_NODES; base += 1024) {
    int i = base + tid;
    int v = (i < N_NODES) ? cursor[i] : 0;
    int x = v;
#pragma unroll
    for (int off = 1; off < 64; off <<= 1) {
      int t = __shfl_up(x, off, 64);
      if (lane >= off) x += t;
    }
    if (lane == 63) wsum[wid] = x;
    __syncthreads();
    if (wid == 0) {
      int s = (lane < 16) ? wsum[lane] : 0;
      int y = s;
#pragma unroll
      for (int off = 1; off < 16; off <<= 1) {
        int t = __shfl_up(y, off, 64);
        if (lane >= off) y += t;
      }
      if (lane < 16) wsum[lane] = y - s;
      if (lane == 15) chunk_total = y;
    }
    __syncthreads();
    int excl = carry + wsum[wid] + (x - v);
    if (i < N_NODES) { offs[i] = excl; cursor[i] = excl; }
    __syncthreads();
    if (tid == 0) carry += chunk_total;
    __syncthreads();
  }
  if (tid == 0) offs[N_NODES] = carry;
}

// ---------------------------------------------------------------------------
// K2: place (src, w) pairs into CSR slots
// ---------------------------------------------------------------------------
__global__ __launch_bounds__(256) void k_place(
    const int* __restrict__ src, const int* __restrict__ dst,
    const float* __restrict__ ew, int* __restrict__ cursor,
    int2* __restrict__ pairs) {
  int e = blockIdx.x * 256 + threadIdx.x;
  if (e < N_EDGES) {
    int p = atomicAdd(&cursor[dst[e]], 1);
    pairs[p] = make_int2(src[e], __float_as_int(ew[e]));
  }
}

// ---------------------------------------------------------------------------
// K3: feat fp32 -> bf16 into A1 columns 0..127 (row stride 256 bf16)
// ---------------------------------------------------------------------------
__global__ __launch_bounds__(256) void k_convert(
    const float* __restrict__ feat, unsigned* __restrict__ A1u) {
  long long idx = (long long)blockIdx.x * 256 + threadIdx.x;  // 1.6M threads
  long long fidx = idx * 8;
  if (fidx >= (long long)N_NODES * IN_F) return;
  int node = (int)(fidx >> 7);
  int c0 = (int)(fidx & 127);
  float4 f0 = *reinterpret_cast<const float4*>(feat + fidx);
  float4 f1 = *reinterpret_cast<const float4*>(feat + fidx + 4);
  uint4 o;
  o.x = f2bf_pair(f0.x, f0.y);
  o.y = f2bf_pair(f0.z, f0.w);
  o.z = f2bf_pair(f1.x, f1.y);
  o.w = f2bf_pair(f1.z, f1.w);
  *reinterpret_cast<uint4*>(A1u + (size_t)node * 128 + (c0 >> 1)) = o;
}

// ---------------------------------------------------------------------------
// K4: build W1T[c][k] = bf16( k<128 ? Wself[k][c] : Wneigh[k-128][c] )
// ---------------------------------------------------------------------------
__global__ __launch_bounds__(256) void k_prepw(
    const float* __restrict__ Wself, const float* __restrict__ Wneigh,
    unsigned short* __restrict__ W1T) {
  int c = blockIdx.x;     // 0..255
  int k = threadIdx.x;    // 0..255
  float v = (k < 128) ? Wself[(size_t)k * HID_F + c]
                      : Wneigh[(size_t)(k - 128) * HID_F + c];
  W1T[(size_t)c * 256 + k] = f2bf(v);
}

// ---------------------------------------------------------------------------
// K5: pull-gather -> A1 columns 128..255 (bf16, pre-normalized by deg)
// ---------------------------------------------------------------------------
__global__ __launch_bounds__(256) void k_gather(
    const float* __restrict__ feat, const int* __restrict__ offs,
    const int2* __restrict__ pairs, unsigned* __restrict__ A1u) {
  int node = blockIdx.x * 4 + (threadIdx.x >> 6);
  if (node >= N_NODES) return;
  int lane = threadIdx.x & 63;
  int start = offs[node], end = offs[node + 1];
  int deg = end - start;
  float2 acc = make_float2(0.f, 0.f);
  for (int k0 = start; k0 < end; k0 += 64) {
    int2 pr = make_int2(0, 0);
    if (k0 + lane < end) pr = pairs[k0 + lane];
    int cnt = min(64, end - k0);
    for (int k = 0; k < cnt; ++k) {
      int s = __shfl(pr.x, k, 64);
      float w = __int_as_float(__shfl(pr.y, k, 64));
      const float2 f = *reinterpret_cast<const float2*>(
          feat + (size_t)s * IN_F + lane * 2);
      acc.x = fmaf(w, f.x, acc.x);
      acc.y = fmaf(w, f.y, acc.y);
    }
  }
  float inv = (deg > 0) ? (1.0f / (float)deg) : 0.f;
  A1u[(size_t)node * 128 + 64 + lane] = f2bf_pair(acc.x * inv, acc.y * inv);
}

// ---------------------------------------------------------------------------
// K6: GEMM1 (MFMA bf16): y = relu(A1 @ W1 + bias), y stored bf16.
//     + fused BN column stats (colsum/colsq).
// Tile 128x256, BK=64, 512 threads = 8 waves (2 x 4), wave tile 64x64.
// ---------------------------------------------------------------------------
__global__ __launch_bounds__(512) void k_gemm1(
    const unsigned short* __restrict__ A1, const unsigned short* __restrict__ W1T,
    const float* __restrict__ bias, unsigned short* __restrict__ y,
    float* __restrict__ colsum, float* __restrict__ colsq) {
  __shared__ short As[128 * 72];   // [row][k] pad 64->72
  __shared__ short Bs[256 * 72];   // [col][k] pad
  __shared__ float csum[256], csq[256];

  const int tid = threadIdx.x;
  const int lane = tid & 63;
  const int wid = tid >> 6;
  const int wr = wid >> 2, wc = wid & 3;
  const int l16 = lane & 15, lk = lane >> 4;
  const int row0 = blockIdx.x * 128;

  const int sr = tid >> 3;        // 0..63 staging row
  const int sc = (tid & 7) * 8;   // k-chunk within BK

  f32x4 acc[4][4];
#pragma unroll
  for (int m = 0; m < 4; ++m)
#pragma unroll
    for (int n = 0; n < 4; ++n) acc[m][n] = (f32x4){0.f, 0.f, 0.f, 0.f};

  for (int ks = 0; ks < 4; ++ks) {
    const int k0 = ks * 64;
    // stage A: 128 rows x 64 k (2 passes of 64 rows)
#pragma unroll
    for (int p = 0; p < 2; ++p) {
      int r = p * 64 + sr;
      int gr = row0 + r;
      bf16x8 v = {};
      if (gr < N_NODES)
        v = *reinterpret_cast<const bf16x8*>(A1 + (size_t)gr * 256 + k0 + sc);
      *reinterpret_cast<bf16x8*>(&As[r * 72 + sc]) = v;
    }
    // stage B: 256 cols x 64 k (4 passes)
#pragma unroll
    for (int p = 0; p < 4; ++p) {
      int c = p * 64 + sr;
      bf16x8 v = *reinterpret_cast<const bf16x8*>(
          W1T + (size_t)c * 256 + k0 + sc);
      *reinterpret_cast<bf16x8*>(&Bs[c * 72 + sc]) = v;
    }
    __syncthreads();

#pragma unroll
    for (int kk = 0; kk < 2; ++kk) {
      bf16x8 af[4], bfr[4];
#pragma unroll
      for (int m = 0; m < 4; ++m)
        af[m] = *reinterpret_cast<const bf16x8*>(
            &As[(wr * 64 + m * 16 + l16) * 72 + kk * 32 + lk * 8]);
#pragma unroll
      for (int n = 0; n < 4; ++n)
        bfr[n] = *reinterpret_cast<const bf16x8*>(
            &Bs[(wc * 64 + n * 16 + l16) * 72 + kk * 32 + lk * 8]);
#pragma unroll
      for (int m = 0; m < 4; ++m)
#pragma unroll
        for (int n = 0; n < 4; ++n)
          acc[m][n] = __builtin_amdgcn_mfma_f32_16x16x32_bf16(
              af[m], bfr[n], acc[m][n], 0, 0, 0);
    }
    __syncthreads();
  }

  // epilogue: bias + relu + bf16 store + BN col stats
  for (int i = tid; i < 256; i += 512) { csum[i] = 0.f; csq[i] = 0.f; }
  __syncthreads();

  float ps[4] = {0.f, 0.f, 0.f, 0.f};
  float qs[4] = {0.f, 0.f, 0.f, 0.f};
#pragma unroll
  for (int n = 0; n < 4; ++n) {
    const int c = wc * 64 + n * 16 + l16;
    const float bb = bias[c];
#pragma unroll
    for (int m = 0; m < 4; ++m) {
      const int rbase = row0 + wr * 64 + m * 16 + lk * 4;
#pragma unroll
      for (int r = 0; r < 4; ++r) {
        int gr = rbase + r;
        if (gr < N_NODES) {
          float t = fmaxf(acc[m][n][r] + bb, 0.f);
          ps[n] += t;
          qs[n] += t * t;
          y[(size_t)gr * 256 + c] = f2bf(t);
        }
      }
    }
  }
#pragma unroll
  for (int n = 0; n < 4; ++n) {
    ps[n] += __shfl_xor(ps[n], 16, 64);
    ps[n] += __shfl_xor(ps[n], 32, 64);
    qs[n] += __shfl_xor(qs[n], 16, 64);
    qs[n] += __shfl_xor(qs[n], 32, 64);
    if (lk == 0) {
      atomicAdd(&csum[wc * 64 + n * 16 + l16], ps[n]);
      atomicAdd(&csq[wc * 64 + n * 16 + l16], qs[n]);
    }
  }
  __syncthreads();
  for (int i = tid; i < 256; i += 512) {
    atomicAdd(&colsum[i], csum[i]);
    atomicAdd(&colsq[i], csq[i]);
  }
}

// ---------------------------------------------------------------------------
// K7: BN fold -> W2T[o][h] bf16 (o padded to 192), b2[o] f32
// ---------------------------------------------------------------------------
__global__ __launch_bounds__(256) void k_finalize(
    const float* __restrict__ colsum, const float* __restrict__ colsq,
    const float* __restrict__ gamma, const float* __restrict__ beta,
    const float* __restrict__ fcW, const float* __restrict__ fcb,
    unsigned short* __restrict__ W2T, float* __restrict__ b2) {
  const float invN = 1.0f / (float)N_NODES;
  if (blockIdx.x < 192) {
    int o = blockIdx.x, h = threadIdx.x;
    unsigned short v = 0;
    if (o < OUT_F) {
      float mu = colsum[h] * invN;
      float var = colsq[h] * invN - mu * mu;
      float rs = rsqrtf(var + BN_EPS) * gamma[h];
      v = f2bf(fcW[(size_t)h * OUT_F + o] * rs);
    }
    W2T[(size_t)o * 256 + h] = v;
  } else if (threadIdx.x < OUT_F) {
    int o = threadIdx.x;
    float acc = fcb[o];
    for (int h = 0; h < HID_F; ++h) {
      float mu = colsum[h] * invN;
      float var = colsq[h] * invN - mu * mu;
      float rs = rsqrtf(var + BN_EPS) * gamma[h];
      acc += (beta[h] - mu * rs) * fcW[(size_t)h * OUT_F + o];
    }
    b2[o] = acc;
  }
}

// ---------------------------------------------------------------------------
// K8: GEMM2 (MFMA bf16): out = y @ W2 + b2.
// Tile 128x192, BK=64, 512 threads = 8 waves (2 x 4), wave tile 64x48.
// ---------------------------------------------------------------------------
__global__ __launch_bounds__(512) void k_gemm2(
    const unsigned short* __restrict__ y, const unsigned short* __restrict__ W2T,
    const float* __restrict__ b2, float* __restrict__ out) {
  __shared__ short As[128 * 72];
  __shared__ short Bs[192 * 72];

  const int tid = threadIdx.x;
  const int lane = tid & 63;
  const int wid = tid >> 6;
  const int wr = wid >> 2, wc = wid & 3;
  const int l16 = lane & 15, lk = lane >> 4;
  const int row0 = blockIdx.x * 128;

  const int sr = tid >> 3;
  const int sc = (tid & 7) * 8;

  f32x4 acc[4][3];
#pragma unroll
  for (int m = 0; m < 4; ++m)
#pragma unroll
    for (int n = 0; n < 3; ++n) acc[m][n] = (f32x4){0.f, 0.f, 0.f, 0.f};

  for (int ks = 0; ks < 4; ++ks) {
    const int k0 = ks * 64;
#pragma unroll
    for (int p = 0; p < 2; ++p) {
      int r = p * 64 + sr;
      int gr = row0 + r;
      bf16x8 v = {};
      if (gr < N_NODES)
        v = *reinterpret_cast<const bf16x8*>(y + (size_t)gr * 256 + k0 + sc);
      *reinterpret_cast<bf16x8*>(&As[r * 72 + sc]) = v;
    }
#pragma unroll
    for (int p = 0; p < 3; ++p) {
      int c = p * 64 + sr;
      bf16x8 v = *reinterpret_cast<const bf16x8*>(
          W2T + (size_t)c * 256 + k0 + sc);
      *reinterpret_cast<bf16x8*>(&Bs[c * 72 + sc]) = v;
    }
    __syncthreads();

#pragma unroll
    for (int kk = 0; kk < 2; ++kk) {
      bf16x8 af[4], bfr[3];
#pragma unroll
      for (int m = 0; m < 4; ++m)
        af[m] = *reinterpret_cast<const bf16x8*>(
            &As[(wr * 64 + m * 16 + l16) * 72 + kk * 32 + lk * 8]);
#pragma unroll
      for (int n = 0; n < 3; ++n)
        bfr[n] = *reinterpret_cast<const bf16x8*>(
            &Bs[(wc * 48 + n * 16 + l16) * 72 + kk * 32 + lk * 8]);
#pragma unroll
      for (int m = 0; m < 4; ++m)
#pragma unroll
        for (int n = 0; n < 3; ++n)
          acc[m][n] = __builtin_amdgcn_mfma_f32_16x16x32_bf16(
              af[m], bfr[n], acc[m][n], 0, 0, 0);
    }
    __syncthreads();
  }

#pragma unroll
  for (int n = 0; n < 3; ++n) {
    const int c = wc * 48 + n * 16 + l16;
    if (c < OUT_F) {
      const float bb = b2[c];
#pragma unroll
      for (int m = 0; m < 4; ++m) {
        const int rbase = row0 + wr * 64 + m * 16 + lk * 4;
#pragma unroll
        for (int r = 0; r < 4; ++r) {
          int gr = rbase + r;
          if (gr < N_NODES)
            out[(size_t)gr * OUT_F + c] = acc[m][n][r] + bb;
        }
      }
    }
  }
}

// ---------------------------------------------------------------------------
extern "C" void kernel_launch(void* const* d_in, const int* in_sizes, int n_in,
                              void* d_out, int out_size, void* d_ws,
                              size_t ws_size, hipStream_t stream) {
  const float* feat   = (const float*)d_in[0];
  const int*   src    = (const int*)d_in[1];
  const int*   dst    = (const int*)d_in[2];
  const float* ew     = (const float*)d_in[3];
  const float* Wself  = (const float*)d_in[4];
  const float* Wneigh = (const float*)d_in[5];
  const float* bias   = (const float*)d_in[6];
  const float* gamma  = (const float*)d_in[7];
  const float* beta   = (const float*)d_in[8];
  const float* fcW    = (const float*)d_in[9];
  const float* fcb    = (const float*)d_in[10];
  float* out = (float*)d_out;

  char* ws = (char*)d_ws;
  // layout (bytes):
  //   [0,           400,000)   cursor  N i32           (zeroed)
  //   [400,000,     401,024)   colsum  256 f32         (zeroed)
  //   [401,024,     402,048)   colsq   256 f32         (zeroed)
  //   [402,048,     802,064)   offs    (N+1) i32
  //   [802,176,  13,602,176)   pairs   E int2
  //   [13,602,176, 64,802,176) A1      N*256 bf16  (feat | neigh)
  //   [64,802,176, 64,933,248) W1T     256*256 bf16
  //   [64,933,248, 65,031,552) W2T     192*256 bf16
  //   [65,031,552, 65,032,192) b2      160 f32
  //   [65,032,192,116,232,192) y       N*256 bf16
  int*            cursor = (int*)(ws + 0);
  float*          colsum = (float*)(ws + 400000);
  float*          colsq  = (float*)(ws + 401024);
  int*            offs   = (int*)(ws + 402048);
  int2*           pairs  = (int2*)(ws + 802176);
  unsigned*       A1u    = (unsigned*)(ws + 13602176);
  unsigned short* A1     = (unsigned short*)(ws + 13602176);
  unsigned short* W1T    = (unsigned short*)(ws + 64802176);
  unsigned short* W2T    = (unsigned short*)(ws + 64933248);
  float*          b2     = (float*)(ws + 65031552);
  unsigned short* y      = (unsigned short*)(ws + 65032192);

  hipMemsetAsync(ws, 0, 402048, stream);

  dim3 b256(256);
  k_hist<<<dim3((N_EDGES + 255) / 256), b256, 0, stream>>>(dst, cursor);
  k_scan<<<dim3(1), dim3(1024), 0, stream>>>(cursor, offs);
  k_place<<<dim3((N_EDGES + 255) / 256), b256, 0, stream>>>(
      src, dst, ew, cursor, pairs);
  k_convert<<<dim3((N_NODES * IN_F / 8 + 255) / 256), b256, 0, stream>>>(
      feat, A1u);
  k_prepw<<<dim3(256), b256, 0, stream>>>(Wself, Wneigh, W1T);
  k_gather<<<dim3((N_NODES + 3) / 4), b256, 0, stream>>>(
      feat, offs, pairs, A1u);
  k_gemm1<<<dim3((N_NODES + 127) / 128), dim3(512), 0, stream>>>(
      A1, W1T, bias, y, colsum, colsq);
  k_finalize<<<dim3(193), b256, 0, stream>>>(
      colsum, colsq, gamma, beta, fcW, fcb, W2T, b2);
  k_gemm2<<<dim3((N_NODES + 127) / 128), dim3(512), 0, stream>>>(
      y, W2T, b2, out);
}

// Round 5
// 412.900 us; speedup vs baseline: 1.3743x; 1.3743x over previous
//
#include <hip/hip_runtime.h>
#include <hip/hip_fp16.h>

#define N_NODES 100000
#define N_EDGES 1600000
#define IN_F    128
#define HID_F   256
#define OUT_F   160
#define BN_EPS  1e-5f

#define EPB     4096                         // edges per chunk
#define NCHUNK  ((N_EDGES + EPB - 1) / EPB)  // 391
#define NPP     (N_NODES / 8)                // 12500 nodes per XCD partition
#define SCHUNK  ((N_NODES + 1023) / 1024)    // 98 scan chunks

typedef __attribute__((ext_vector_type(8))) short bf16x8;
typedef __attribute__((ext_vector_type(4))) float f32x4;

static __device__ inline unsigned short f2bf(float x) {
  unsigned u = __float_as_uint(x);
  return (unsigned short)((u + 0x7fffu + ((u >> 16) & 1u)) >> 16);
}
static __device__ inline unsigned f2bf_pair(float lo, float hi) {
  return (unsigned)f2bf(lo) | ((unsigned)f2bf(hi) << 16);
}

// ---------------------------------------------------------------------------
// K0: XCD-partitioned histogram. Block p=blockIdx&7 counts only dst in its
// 12500-node partition -> cursor atomics stay in that XCD's L2.
// ---------------------------------------------------------------------------
__global__ __launch_bounds__(256) void k_hist(const int* __restrict__ dst,
                                              int* __restrict__ cursor) {
  const int p = blockIdx.x & 7;
  const int e0 = (blockIdx.x >> 3) * EPB + threadIdx.x;
  const int lo = p * NPP, hi = lo + NPP;
#pragma unroll
  for (int i = 0; i < EPB / 256; ++i) {
    int e = e0 + i * 256;
    if (e < N_EDGES) {
      int d = dst[e];
      if (d >= lo && d < hi) atomicAdd(&cursor[d], 1);
    }
  }
}

// ---------------------------------------------------------------------------
// K1a: per-chunk scan (98 blocks x 1024). offs[i] = chunk-local exclusive.
// ---------------------------------------------------------------------------
__global__ __launch_bounds__(1024) void k_scan1(const int* __restrict__ cursor,
                                                int* __restrict__ offs,
                                                int* __restrict__ totals) {
  __shared__ int wsum[16];
  __shared__ int ctot;
  const int tid = threadIdx.x, lane = tid & 63, wid = tid >> 6;
  int i = blockIdx.x * 1024 + tid;
  int v = (i < N_NODES) ? cursor[i] : 0;
  int x = v;
#pragma unroll
  for (int off = 1; off < 64; off <<= 1) {
    int t = __shfl_up(x, off, 64);
    if (lane >= off) x += t;
  }
  if (lane == 63) wsum[wid] = x;
  __syncthreads();
  if (wid == 0) {
    int s = (lane < 16) ? wsum[lane] : 0;
    int y = s;
#pragma unroll
    for (int off = 1; off < 16; off <<= 1) {
      int t = __shfl_up(y, off, 64);
      if (lane >= off) y += t;
    }
    if (lane < 16) wsum[lane] = y - s;
    if (lane == 15) ctot = y;
  }
  __syncthreads();
  if (i < N_NODES) offs[i] = wsum[wid] + (x - v);
  if (tid == 0) totals[blockIdx.x] = ctot;
}

// ---------------------------------------------------------------------------
// K1b: scan the 98 chunk totals -> bases (1 block, 128 threads = 2 waves)
// ---------------------------------------------------------------------------
__global__ __launch_bounds__(128) void k_scan2(const int* __restrict__ totals,
                                               int* __restrict__ bases) {
  __shared__ int w0t;
  const int tid = threadIdx.x, lane = tid & 63;
  int t = (tid < SCHUNK) ? totals[tid] : 0;
  int x = t;
#pragma unroll
  for (int off = 1; off < 64; off <<= 1) {
    int q = __shfl_up(x, off, 64);
    if (lane >= off) x += q;
  }
  if (tid == 63) w0t = x;
  __syncthreads();
  int excl = x - t + ((tid >= 64) ? w0t : 0);
  if (tid < SCHUNK) bases[tid] = excl;
}

// ---------------------------------------------------------------------------
// K1c: add bases -> final exclusive offsets in offs AND cursor
// ---------------------------------------------------------------------------
__global__ __launch_bounds__(256) void k_scan3(int* __restrict__ offs,
                                               int* __restrict__ cursor,
                                               const int* __restrict__ bases) {
  int i = blockIdx.x * 256 + threadIdx.x;
  if (i < N_NODES) {
    int o = offs[i] + bases[i >> 10];
    offs[i] = o;
    cursor[i] = o;
  }
  if (i == 0) offs[N_NODES] = N_EDGES;
}

// ---------------------------------------------------------------------------
// K2: XCD-partitioned place. pairs[slot] = (src<<15) | (fp16(w) & 0x7fff).
// Slots for partition p live in a contiguous ~1.6MB region -> L2-local.
// ---------------------------------------------------------------------------
__global__ __launch_bounds__(256) void k_place(
    const int* __restrict__ src, const int* __restrict__ dst,
    const float* __restrict__ ew, int* __restrict__ cursor,
    unsigned* __restrict__ pairs) {
  const int p = blockIdx.x & 7;
  const int e0 = (blockIdx.x >> 3) * EPB + threadIdx.x;
  const int lo = p * NPP, hi = lo + NPP;
#pragma unroll
  for (int i = 0; i < EPB / 256; ++i) {
    int e = e0 + i * 256;
    if (e < N_EDGES) {
      int d = dst[e];
      if (d >= lo && d < hi) {
        unsigned hb = (unsigned)__half_as_ushort(__float2half(ew[e])) & 0x7fffu;
        int slot = atomicAdd(&cursor[d], 1);
        pairs[slot] = ((unsigned)src[e] << 15) | hb;
      }
    }
  }
}

// ---------------------------------------------------------------------------
// K3: feat fp32 -> bf16 into A1 columns 0..127 (row stride 256 bf16)
// ---------------------------------------------------------------------------
__global__ __launch_bounds__(256) void k_convert(
    const float* __restrict__ feat, unsigned* __restrict__ A1u) {
  long long idx = (long long)blockIdx.x * 256 + threadIdx.x;
  long long fidx = idx * 8;
  if (fidx >= (long long)N_NODES * IN_F) return;
  int node = (int)(fidx >> 7);
  int c0 = (int)(fidx & 127);
  float4 f0 = *reinterpret_cast<const float4*>(feat + fidx);
  float4 f1 = *reinterpret_cast<const float4*>(feat + fidx + 4);
  uint4 o;
  o.x = f2bf_pair(f0.x, f0.y);
  o.y = f2bf_pair(f0.z, f0.w);
  o.z = f2bf_pair(f1.x, f1.y);
  o.w = f2bf_pair(f1.z, f1.w);
  *reinterpret_cast<uint4*>(A1u + (size_t)node * 128 + (c0 >> 1)) = o;
}

// ---------------------------------------------------------------------------
// K4: W1T[c][k] = bf16( k<128 ? Wself[k][c] : Wneigh[k-128][c] )
// ---------------------------------------------------------------------------
__global__ __launch_bounds__(256) void k_prepw(
    const float* __restrict__ Wself, const float* __restrict__ Wneigh,
    unsigned short* __restrict__ W1T) {
  int c = blockIdx.x;
  int k = threadIdx.x;
  float v = (k < 128) ? Wself[(size_t)k * HID_F + c]
                      : Wneigh[(size_t)(k - 128) * HID_F + c];
  W1T[(size_t)c * 256 + k] = f2bf(v);
}

// ---------------------------------------------------------------------------
// K5: pull-gather from bf16 A1 feat cols -> A1 neigh cols (bf16).
// One wave per node; lane owns u32 j=lane (feat cols 2j,2j+1).
// ---------------------------------------------------------------------------
__global__ __launch_bounds__(256) void k_gather(
    const int* __restrict__ offs, const unsigned* __restrict__ pairs,
    unsigned* __restrict__ A1u) {
  int node = blockIdx.x * 4 + (threadIdx.x >> 6);
  if (node >= N_NODES) return;
  int lane = threadIdx.x & 63;
  int start = offs[node], end = offs[node + 1];
  int deg = end - start;
  float2 acc = make_float2(0.f, 0.f);
  for (int k0 = start; k0 < end; k0 += 64) {
    unsigned pr = 0;
    if (k0 + lane < end) pr = pairs[k0 + lane];
    int cnt = min(64, end - k0);
    for (int k = 0; k < cnt; ++k) {
      unsigned uu = (unsigned)__shfl((int)pr, k, 64);
      int s = (int)(uu >> 15);
      float w = __half2float(__ushort_as_half((unsigned short)(uu & 0x7fffu)));
      unsigned f = A1u[(size_t)s * 128 + lane];
      float flo = __uint_as_float(f << 16);
      float fhi = __uint_as_float(f & 0xffff0000u);
      acc.x = fmaf(w, flo, acc.x);
      acc.y = fmaf(w, fhi, acc.y);
    }
  }
  float inv = (deg > 0) ? (1.0f / (float)deg) : 0.f;
  A1u[(size_t)node * 128 + 64 + lane] = f2bf_pair(acc.x * inv, acc.y * inv);
}

// ---------------------------------------------------------------------------
// K6: GEMM1 (MFMA bf16): y = relu(A1 @ W1 + bias) bf16 + BN col stats.
// Tile 128x256, BK=64, 512 threads = 8 waves, wave tile 64x64.
// ---------------------------------------------------------------------------
__global__ __launch_bounds__(512) void k_gemm1(
    const unsigned short* __restrict__ A1, const unsigned short* __restrict__ W1T,
    const float* __restrict__ bias, unsigned short* __restrict__ y,
    float* __restrict__ colsum, float* __restrict__ colsq) {
  __shared__ short As[128 * 72];
  __shared__ short Bs[256 * 72];
  __shared__ float csum[256], csq[256];

  const int tid = threadIdx.x;
  const int lane = tid & 63;
  const int wid = tid >> 6;
  const int wr = wid >> 2, wc = wid & 3;
  const int l16 = lane & 15, lk = lane >> 4;
  const int row0 = blockIdx.x * 128;

  const int sr = tid >> 3;
  const int sc = (tid & 7) * 8;

  f32x4 acc[4][4];
#pragma unroll
  for (int m = 0; m < 4; ++m)
#pragma unroll
    for (int n = 0; n < 4; ++n) acc[m][n] = (f32x4){0.f, 0.f, 0.f, 0.f};

  for (int ks = 0; ks < 4; ++ks) {
    const int k0 = ks * 64;
#pragma unroll
    for (int p = 0; p < 2; ++p) {
      int r = p * 64 + sr;
      int gr = row0 + r;
      bf16x8 v = {};
      if (gr < N_NODES)
        v = *reinterpret_cast<const bf16x8*>(A1 + (size_t)gr * 256 + k0 + sc);
      *reinterpret_cast<bf16x8*>(&As[r * 72 + sc]) = v;
    }
#pragma unroll
    for (int p = 0; p < 4; ++p) {
      int c = p * 64 + sr;
      bf16x8 v = *reinterpret_cast<const bf16x8*>(
          W1T + (size_t)c * 256 + k0 + sc);
      *reinterpret_cast<bf16x8*>(&Bs[c * 72 + sc]) = v;
    }
    __syncthreads();

#pragma unroll
    for (int kk = 0; kk < 2; ++kk) {
      bf16x8 af[4], bfr[4];
#pragma unroll
      for (int m = 0; m < 4; ++m)
        af[m] = *reinterpret_cast<const bf16x8*>(
            &As[(wr * 64 + m * 16 + l16) * 72 + kk * 32 + lk * 8]);
#pragma unroll
      for (int n = 0; n < 4; ++n)
        bfr[n] = *reinterpret_cast<const bf16x8*>(
            &Bs[(wc * 64 + n * 16 + l16) * 72 + kk * 32 + lk * 8]);
#pragma unroll
      for (int m = 0; m < 4; ++m)
#pragma unroll
        for (int n = 0; n < 4; ++n)
          acc[m][n] = __builtin_amdgcn_mfma_f32_16x16x32_bf16(
              af[m], bfr[n], acc[m][n], 0, 0, 0);
    }
    __syncthreads();
  }

  for (int i = tid; i < 256; i += 512) { csum[i] = 0.f; csq[i] = 0.f; }
  __syncthreads();

  float ps[4] = {0.f, 0.f, 0.f, 0.f};
  float qs[4] = {0.f, 0.f, 0.f, 0.f};
#pragma unroll
  for (int n = 0; n < 4; ++n) {
    const int c = wc * 64 + n * 16 + l16;
    const float bb = bias[c];
#pragma unroll
    for (int m = 0; m < 4; ++m) {
      const int rbase = row0 + wr * 64 + m * 16 + lk * 4;
#pragma unroll
      for (int r = 0; r < 4; ++r) {
        int gr = rbase + r;
        if (gr < N_NODES) {
          float t = fmaxf(acc[m][n][r] + bb, 0.f);
          ps[n] += t;
          qs[n] += t * t;
          y[(size_t)gr * 256 + c] = f2bf(t);
        }
      }
    }
  }
#pragma unroll
  for (int n = 0; n < 4; ++n) {
    ps[n] += __shfl_xor(ps[n], 16, 64);
    ps[n] += __shfl_xor(ps[n], 32, 64);
    qs[n] += __shfl_xor(qs[n], 16, 64);
    qs[n] += __shfl_xor(qs[n], 32, 64);
    if (lk == 0) {
      atomicAdd(&csum[wc * 64 + n * 16 + l16], ps[n]);
      atomicAdd(&csq[wc * 64 + n * 16 + l16], qs[n]);
    }
  }
  __syncthreads();
  for (int i = tid; i < 256; i += 512) {
    atomicAdd(&colsum[i], csum[i]);
    atomicAdd(&colsq[i], csq[i]);
  }
}

// ---------------------------------------------------------------------------
// K7: BN fold -> W2T[o][h] bf16 (o padded to 192), b2[o] f32
// ---------------------------------------------------------------------------
__global__ __launch_bounds__(256) void k_finalize(
    const float* __restrict__ colsum, const float* __restrict__ colsq,
    const float* __restrict__ gamma, const float* __restrict__ beta,
    const float* __restrict__ fcW, const float* __restrict__ fcb,
    unsigned short* __restrict__ W2T, float* __restrict__ b2) {
  const float invN = 1.0f / (float)N_NODES;
  if (blockIdx.x < 192) {
    int o = blockIdx.x, h = threadIdx.x;
    unsigned short v = 0;
    if (o < OUT_F) {
      float mu = colsum[h] * invN;
      float var = colsq[h] * invN - mu * mu;
      float rs = rsqrtf(var + BN_EPS) * gamma[h];
      v = f2bf(fcW[(size_t)h * OUT_F + o] * rs);
    }
    W2T[(size_t)o * 256 + h] = v;
  } else if (threadIdx.x < OUT_F) {
    int o = threadIdx.x;
    float acc = fcb[o];
    for (int h = 0; h < HID_F; ++h) {
      float mu = colsum[h] * invN;
      float var = colsq[h] * invN - mu * mu;
      float rs = rsqrtf(var + BN_EPS) * gamma[h];
      acc += (beta[h] - mu * rs) * fcW[(size_t)h * OUT_F + o];
    }
    b2[o] = acc;
  }
}

// ---------------------------------------------------------------------------
// K8: GEMM2 (MFMA bf16): out = y @ W2 + b2. Tile 128x192, BK=64, 8 waves.
// ---------------------------------------------------------------------------
__global__ __launch_bounds__(512) void k_gemm2(
    const unsigned short* __restrict__ y, const unsigned short* __restrict__ W2T,
    const float* __restrict__ b2, float* __restrict__ out) {
  __shared__ short As[128 * 72];
  __shared__ short Bs[192 * 72];

  const int tid = threadIdx.x;
  const int lane = tid & 63;
  const int wid = tid >> 6;
  const int wr = wid >> 2, wc = wid & 3;
  const int l16 = lane & 15, lk = lane >> 4;
  const int row0 = blockIdx.x * 128;

  const int sr = tid >> 3;
  const int sc = (tid & 7) * 8;

  f32x4 acc[4][3];
#pragma unroll
  for (int m = 0; m < 4; ++m)
#pragma unroll
    for (int n = 0; n < 3; ++n) acc[m][n] = (f32x4){0.f, 0.f, 0.f, 0.f};

  for (int ks = 0; ks < 4; ++ks) {
    const int k0 = ks * 64;
#pragma unroll
    for (int p = 0; p < 2; ++p) {
      int r = p * 64 + sr;
      int gr = row0 + r;
      bf16x8 v = {};
      if (gr < N_NODES)
        v = *reinterpret_cast<const bf16x8*>(y + (size_t)gr * 256 + k0 + sc);
      *reinterpret_cast<bf16x8*>(&As[r * 72 + sc]) = v;
    }
#pragma unroll
    for (int p = 0; p < 3; ++p) {
      int c = p * 64 + sr;
      bf16x8 v = *reinterpret_cast<const bf16x8*>(
          W2T + (size_t)c * 256 + k0 + sc);
      *reinterpret_cast<bf16x8*>(&Bs[c * 72 + sc]) = v;
    }
    __syncthreads();

#pragma unroll
    for (int kk = 0; kk < 2; ++kk) {
      bf16x8 af[4], bfr[3];
#pragma unroll
      for (int m = 0; m < 4; ++m)
        af[m] = *reinterpret_cast<const bf16x8*>(
            &As[(wr * 64 + m * 16 + l16) * 72 + kk * 32 + lk * 8]);
#pragma unroll
      for (int n = 0; n < 3; ++n)
        bfr[n] = *reinterpret_cast<const bf16x8*>(
            &Bs[(wc * 48 + n * 16 + l16) * 72 + kk * 32 + lk * 8]);
#pragma unroll
      for (int m = 0; m < 4; ++m)
#pragma unroll
        for (int n = 0; n < 3; ++n)
          acc[m][n] = __builtin_amdgcn_mfma_f32_16x16x32_bf16(
              af[m], bfr[n], acc[m][n], 0, 0, 0);
    }
    __syncthreads();
  }

#pragma unroll
  for (int n = 0; n < 3; ++n) {
    const int c = wc * 48 + n * 16 + l16;
    if (c < OUT_F) {
      const float bb = b2[c];
#pragma unroll
      for (int m = 0; m < 4; ++m) {
        const int rbase = row0 + wr * 64 + m * 16 + lk * 4;
#pragma unroll
        for (int r = 0; r < 4; ++r) {
          int gr = rbase + r;
          if (gr < N_NODES)
            out[(size_t)gr * OUT_F + c] = acc[m][n][r] + bb;
        }
      }
    }
  }
}

// ---------------------------------------------------------------------------
extern "C" void kernel_launch(void* const* d_in, const int* in_sizes, int n_in,
                              void* d_out, int out_size, void* d_ws,
                              size_t ws_size, hipStream_t stream) {
  const float* feat   = (const float*)d_in[0];
  const int*   src    = (const int*)d_in[1];
  const int*   dst    = (const int*)d_in[2];
  const float* ew     = (const float*)d_in[3];
  const float* Wself  = (const float*)d_in[4];
  const float* Wneigh = (const float*)d_in[5];
  const float* bias   = (const float*)d_in[6];
  const float* gamma  = (const float*)d_in[7];
  const float* beta   = (const float*)d_in[8];
  const float* fcW    = (const float*)d_in[9];
  const float* fcb    = (const float*)d_in[10];
  float* out = (float*)d_out;

  char* ws = (char*)d_ws;
  // layout (bytes):
  //   [0,        400,000)   cursor  N i32            (zeroed)
  //   [400,000,  401,024)   colsum  256 f32          (zeroed)
  //   [401,024,  402,048)   colsq   256 f32          (zeroed)
  //   [402,048,  802,052)   offs    (N+1) i32
  //   [802,304,  802,696)   totals  98 i32
  //   [802,816,  803,208)   bases   98 i32
  //   [803,328,  7,203,328) pairs   E u32
  //   [7,203,328, 58,403,328) A1    N*256 bf16 (feat | neigh)
  //   [58,403,328,58,534,400) W1T   256*256 bf16
  //   [58,534,400,58,632,704) W2T   192*256 bf16
  //   [58,632,704,58,633,344) b2    160 f32
  //   [58,633,344,109,833,344) y    N*256 bf16
  int*            cursor = (int*)(ws + 0);
  float*          colsum = (float*)(ws + 400000);
  float*          colsq  = (float*)(ws + 401024);
  int*            offs   = (int*)(ws + 402048);
  int*            totals = (int*)(ws + 802304);
  int*            bases  = (int*)(ws + 802816);
  unsigned*       pairs  = (unsigned*)(ws + 803328);
  unsigned*       A1u    = (unsigned*)(ws + 7203328);
  unsigned short* A1     = (unsigned short*)(ws + 7203328);
  unsigned short* W1T    = (unsigned short*)(ws + 58403328);
  unsigned short* W2T    = (unsigned short*)(ws + 58534400);
  float*          b2     = (float*)(ws + 58632704);
  unsigned short* y      = (unsigned short*)(ws + 58633344);

  hipMemsetAsync(ws, 0, 402048, stream);

  dim3 b256(256);
  k_convert<<<dim3((N_NODES * IN_F / 8 + 255) / 256), b256, 0, stream>>>(
      feat, A1u);
  k_prepw<<<dim3(256), b256, 0, stream>>>(Wself, Wneigh, W1T);
  k_hist<<<dim3(NCHUNK * 8), b256, 0, stream>>>(dst, cursor);
  k_scan1<<<dim3(SCHUNK), dim3(1024), 0, stream>>>(cursor, offs, totals);
  k_scan2<<<dim3(1), dim3(128), 0, stream>>>(totals, bases);
  k_scan3<<<dim3((N_NODES + 255) / 256), b256, 0, stream>>>(
      offs, cursor, bases);
  k_place<<<dim3(NCHUNK * 8), b256, 0, stream>>>(
      src, dst, ew, cursor, pairs);
  k_gather<<<dim3((N_NODES + 3) / 4), b256, 0, stream>>>(offs, pairs, A1u);
  k_gemm1<<<dim3((N_NODES + 127) / 128), dim3(512), 0, stream>>>(
      A1, W1T, bias, y, colsum, colsq);
  k_finalize<<<dim3(193), b256, 0, stream>>>(
      colsum, colsq, gamma, beta, fcW, fcb, W2T, b2);
  k_gemm2<<<dim3((N_NODES + 127) / 128), dim3(512), 0, stream>>>(
      y, W2T, b2, out);
}

// Round 6
// 371.405 us; speedup vs baseline: 1.5279x; 1.1117x over previous
//
#include <hip/hip_runtime.h>
#include <hip/hip_fp16.h>

#define N_NODES 100000
#define N_EDGES 1600000
#define IN_F    128
#define HID_F   256
#define OUT_F   160
#define BN_EPS  1e-5f

#define EPB     4096                         // edges per chunk
#define NCHUNK  ((N_EDGES + EPB - 1) / EPB)  // 391
#define NPP     (N_NODES / 8)                // 12500 nodes per XCD partition
#define SCHUNK  ((N_NODES + 1023) / 1024)    // 98 scan chunks

typedef __attribute__((ext_vector_type(8))) short bf16x8;
typedef __attribute__((ext_vector_type(4))) float f32x4;

static __device__ inline unsigned short f2bf(float x) {
  unsigned u = __float_as_uint(x);
  return (unsigned short)((u + 0x7fffu + ((u >> 16) & 1u)) >> 16);
}
static __device__ inline unsigned f2bf_pair(float lo, float hi) {
  return (unsigned)f2bf(lo) | ((unsigned)f2bf(hi) << 16);
}
static __device__ inline float bf_lo(unsigned u) {
  return __uint_as_float(u << 16);
}
static __device__ inline float bf_hi(unsigned u) {
  return __uint_as_float(u & 0xffff0000u);
}

// ---------------------------------------------------------------------------
// K0: XCD-partitioned histogram. Block p=blockIdx&7 counts only dst in its
// 12500-node partition -> cursor atomics stay in that XCD's L2.
// ---------------------------------------------------------------------------
__global__ __launch_bounds__(256) void k_hist(const int* __restrict__ dst,
                                              int* __restrict__ cursor) {
  const int p = blockIdx.x & 7;
  const int e0 = (blockIdx.x >> 3) * EPB + threadIdx.x;
  const int lo = p * NPP, hi = lo + NPP;
#pragma unroll
  for (int i = 0; i < EPB / 256; ++i) {
    int e = e0 + i * 256;
    if (e < N_EDGES) {
      int d = dst[e];
      if (d >= lo && d < hi) atomicAdd(&cursor[d], 1);
    }
  }
}

// ---------------------------------------------------------------------------
// K1a: per-chunk scan (98 blocks x 1024). offs[i] = chunk-local exclusive.
// ---------------------------------------------------------------------------
__global__ __launch_bounds__(1024) void k_scan1(const int* __restrict__ cursor,
                                                int* __restrict__ offs,
                                                int* __restrict__ totals) {
  __shared__ int wsum[16];
  __shared__ int ctot;
  const int tid = threadIdx.x, lane = tid & 63, wid = tid >> 6;
  int i = blockIdx.x * 1024 + tid;
  int v = (i < N_NODES) ? cursor[i] : 0;
  int x = v;
#pragma unroll
  for (int off = 1; off < 64; off <<= 1) {
    int t = __shfl_up(x, off, 64);
    if (lane >= off) x += t;
  }
  if (lane == 63) wsum[wid] = x;
  __syncthreads();
  if (wid == 0) {
    int s = (lane < 16) ? wsum[lane] : 0;
    int y = s;
#pragma unroll
    for (int off = 1; off < 16; off <<= 1) {
      int t = __shfl_up(y, off, 64);
      if (lane >= off) y += t;
    }
    if (lane < 16) wsum[lane] = y - s;
    if (lane == 15) ctot = y;
  }
  __syncthreads();
  if (i < N_NODES) offs[i] = wsum[wid] + (x - v);
  if (tid == 0) totals[blockIdx.x] = ctot;
}

// ---------------------------------------------------------------------------
// K1b: scan the 98 chunk totals -> bases (1 block, 128 threads = 2 waves)
// ---------------------------------------------------------------------------
__global__ __launch_bounds__(128) void k_scan2(const int* __restrict__ totals,
                                               int* __restrict__ bases) {
  __shared__ int w0t;
  const int tid = threadIdx.x, lane = tid & 63;
  int t = (tid < SCHUNK) ? totals[tid] : 0;
  int x = t;
#pragma unroll
  for (int off = 1; off < 64; off <<= 1) {
    int q = __shfl_up(x, off, 64);
    if (lane >= off) x += q;
  }
  if (tid == 63) w0t = x;
  __syncthreads();
  int excl = x - t + ((tid >= 64) ? w0t : 0);
  if (tid < SCHUNK) bases[tid] = excl;
}

// ---------------------------------------------------------------------------
// K1c: add bases -> final exclusive offsets in offs AND cursor
// ---------------------------------------------------------------------------
__global__ __launch_bounds__(256) void k_scan3(int* __restrict__ offs,
                                               int* __restrict__ cursor,
                                               const int* __restrict__ bases) {
  int i = blockIdx.x * 256 + threadIdx.x;
  if (i < N_NODES) {
    int o = offs[i] + bases[i >> 10];
    offs[i] = o;
    cursor[i] = o;
  }
  if (i == 0) offs[N_NODES] = N_EDGES;
}

// ---------------------------------------------------------------------------
// K2: XCD-partitioned place. pairs[slot] = (src<<15) | (fp16(w) & 0x7fff).
// ---------------------------------------------------------------------------
__global__ __launch_bounds__(256) void k_place(
    const int* __restrict__ src, const int* __restrict__ dst,
    const float* __restrict__ ew, int* __restrict__ cursor,
    unsigned* __restrict__ pairs) {
  const int p = blockIdx.x & 7;
  const int e0 = (blockIdx.x >> 3) * EPB + threadIdx.x;
  const int lo = p * NPP, hi = lo + NPP;
#pragma unroll
  for (int i = 0; i < EPB / 256; ++i) {
    int e = e0 + i * 256;
    if (e < N_EDGES) {
      int d = dst[e];
      if (d >= lo && d < hi) {
        unsigned hb = (unsigned)__half_as_ushort(__float2half(ew[e])) & 0x7fffu;
        int slot = atomicAdd(&cursor[d], 1);
        pairs[slot] = ((unsigned)src[e] << 15) | hb;
      }
    }
  }
}

// ---------------------------------------------------------------------------
// K3: feat fp32 -> bf16 into A1 columns 0..127 (row stride 256 bf16)
// ---------------------------------------------------------------------------
__global__ __launch_bounds__(256) void k_convert(
    const float* __restrict__ feat, unsigned* __restrict__ A1u) {
  long long idx = (long long)blockIdx.x * 256 + threadIdx.x;
  long long fidx = idx * 8;
  if (fidx >= (long long)N_NODES * IN_F) return;
  int node = (int)(fidx >> 7);
  int c0 = (int)(fidx & 127);
  float4 f0 = *reinterpret_cast<const float4*>(feat + fidx);
  float4 f1 = *reinterpret_cast<const float4*>(feat + fidx + 4);
  uint4 o;
  o.x = f2bf_pair(f0.x, f0.y);
  o.y = f2bf_pair(f0.z, f0.w);
  o.z = f2bf_pair(f1.x, f1.y);
  o.w = f2bf_pair(f1.z, f1.w);
  *reinterpret_cast<uint4*>(A1u + (size_t)node * 128 + (c0 >> 1)) = o;
}

// ---------------------------------------------------------------------------
// K4: W1T[c][k] = bf16( k<128 ? Wself[k][c] : Wneigh[k-128][c] )
// ---------------------------------------------------------------------------
__global__ __launch_bounds__(256) void k_prepw(
    const float* __restrict__ Wself, const float* __restrict__ Wneigh,
    unsigned short* __restrict__ W1T) {
  int c = blockIdx.x;
  int k = threadIdx.x;
  float v = (k < 128) ? Wself[(size_t)k * HID_F + c]
                      : Wneigh[(size_t)(k - 128) * HID_F + c];
  W1T[(size_t)c * 256 + k] = f2bf(v);
}

// ---------------------------------------------------------------------------
// K5: pull-gather, 4-edge-parallel. Wave = 4 groups x 16 lanes; group g
// processes edge 4t+g; each lane loads uint4 (8 bf16 cols) of the src row.
// Every VALU op covers 4 edges. OOB lanes hold pr=0 -> s=0, w=+0 (no-op).
// Cross-group shfl_xor reduce; group 0 writes neigh (256B coalesced).
// ---------------------------------------------------------------------------
__global__ __launch_bounds__(256) void k_gather(
    const int* __restrict__ offs, const unsigned* __restrict__ pairs,
    unsigned* __restrict__ A1u) {
  int node = blockIdx.x * 4 + (threadIdx.x >> 6);
  if (node >= N_NODES) return;
  const int lane = threadIdx.x & 63;
  const int g = lane >> 4;    // edge group 0..3
  const int cl = lane & 15;   // owns u32 words cl*4 .. cl*4+3 (8 bf16 cols)
  const int start = offs[node], end = offs[node + 1];
  const int deg = end - start;

  float acc[8] = {0.f, 0.f, 0.f, 0.f, 0.f, 0.f, 0.f, 0.f};

  for (int k0 = start; k0 < end; k0 += 64) {
    unsigned pr = 0;
    if (k0 + lane < end) pr = pairs[k0 + lane];
    const int cnt = min(64, end - k0);
    const int nsteps = (cnt + 3) >> 2;
    for (int t = 0; t < nsteps; ++t) {
      unsigned uu = (unsigned)__shfl((int)pr, 4 * t + g, 64);
      int s = (int)(uu >> 15);
      float w = __half2float(__ushort_as_half((unsigned short)(uu & 0x7fffu)));
      uint4 f = *reinterpret_cast<const uint4*>(A1u + (size_t)s * 128 + cl * 4);
      acc[0] = fmaf(w, bf_lo(f.x), acc[0]);
      acc[1] = fmaf(w, bf_hi(f.x), acc[1]);
      acc[2] = fmaf(w, bf_lo(f.y), acc[2]);
      acc[3] = fmaf(w, bf_hi(f.y), acc[3]);
      acc[4] = fmaf(w, bf_lo(f.z), acc[4]);
      acc[5] = fmaf(w, bf_hi(f.z), acc[5]);
      acc[6] = fmaf(w, bf_lo(f.w), acc[6]);
      acc[7] = fmaf(w, bf_hi(f.w), acc[7]);
    }
  }

  // reduce across the 4 edge groups (lanes differing in bits 4..5)
#pragma unroll
  for (int i = 0; i < 8; ++i) {
    acc[i] += __shfl_xor(acc[i], 16, 64);
    acc[i] += __shfl_xor(acc[i], 32, 64);
  }

  if (g == 0) {
    const float inv = (deg > 0) ? (1.0f / (float)deg) : 0.f;
    uint4 o;
    o.x = f2bf_pair(acc[0] * inv, acc[1] * inv);
    o.y = f2bf_pair(acc[2] * inv, acc[3] * inv);
    o.z = f2bf_pair(acc[4] * inv, acc[5] * inv);
    o.w = f2bf_pair(acc[6] * inv, acc[7] * inv);
    *reinterpret_cast<uint4*>(A1u + (size_t)node * 128 + 64 + cl * 4) = o;
  }
}

// ---------------------------------------------------------------------------
// K6: GEMM1 (MFMA bf16): y = relu(A1 @ W1 + bias) bf16 + BN col stats.
// Tile 128x256, BK=64, 512 threads = 8 waves, wave tile 64x64.
// ---------------------------------------------------------------------------
__global__ __launch_bounds__(512) void k_gemm1(
    const unsigned short* __restrict__ A1, const unsigned short* __restrict__ W1T,
    const float* __restrict__ bias, unsigned short* __restrict__ y,
    float* __restrict__ colsum, float* __restrict__ colsq) {
  __shared__ short As[128 * 72];
  __shared__ short Bs[256 * 72];
  __shared__ float csum[256], csq[256];

  const int tid = threadIdx.x;
  const int lane = tid & 63;
  const int wid = tid >> 6;
  const int wr = wid >> 2, wc = wid & 3;
  const int l16 = lane & 15, lk = lane >> 4;
  const int row0 = blockIdx.x * 128;

  const int sr = tid >> 3;
  const int sc = (tid & 7) * 8;

  f32x4 acc[4][4];
#pragma unroll
  for (int m = 0; m < 4; ++m)
#pragma unroll
    for (int n = 0; n < 4; ++n) acc[m][n] = (f32x4){0.f, 0.f, 0.f, 0.f};

  for (int ks = 0; ks < 4; ++ks) {
    const int k0 = ks * 64;
#pragma unroll
    for (int p = 0; p < 2; ++p) {
      int r = p * 64 + sr;
      int gr = row0 + r;
      bf16x8 v = {};
      if (gr < N_NODES)
        v = *reinterpret_cast<const bf16x8*>(A1 + (size_t)gr * 256 + k0 + sc);
      *reinterpret_cast<bf16x8*>(&As[r * 72 + sc]) = v;
    }
#pragma unroll
    for (int p = 0; p < 4; ++p) {
      int c = p * 64 + sr;
      bf16x8 v = *reinterpret_cast<const bf16x8*>(
          W1T + (size_t)c * 256 + k0 + sc);
      *reinterpret_cast<bf16x8*>(&Bs[c * 72 + sc]) = v;
    }
    __syncthreads();

#pragma unroll
    for (int kk = 0; kk < 2; ++kk) {
      bf16x8 af[4], bfr[4];
#pragma unroll
      for (int m = 0; m < 4; ++m)
        af[m] = *reinterpret_cast<const bf16x8*>(
            &As[(wr * 64 + m * 16 + l16) * 72 + kk * 32 + lk * 8]);
#pragma unroll
      for (int n = 0; n < 4; ++n)
        bfr[n] = *reinterpret_cast<const bf16x8*>(
            &Bs[(wc * 64 + n * 16 + l16) * 72 + kk * 32 + lk * 8]);
#pragma unroll
      for (int m = 0; m < 4; ++m)
#pragma unroll
        for (int n = 0; n < 4; ++n)
          acc[m][n] = __builtin_amdgcn_mfma_f32_16x16x32_bf16(
              af[m], bfr[n], acc[m][n], 0, 0, 0);
    }
    __syncthreads();
  }

  for (int i = tid; i < 256; i += 512) { csum[i] = 0.f; csq[i] = 0.f; }
  __syncthreads();

  float ps[4] = {0.f, 0.f, 0.f, 0.f};
  float qs[4] = {0.f, 0.f, 0.f, 0.f};
#pragma unroll
  for (int n = 0; n < 4; ++n) {
    const int c = wc * 64 + n * 16 + l16;
    const float bb = bias[c];
#pragma unroll
    for (int m = 0; m < 4; ++m) {
      const int rbase = row0 + wr * 64 + m * 16 + lk * 4;
#pragma unroll
      for (int r = 0; r < 4; ++r) {
        int gr = rbase + r;
        if (gr < N_NODES) {
          float t = fmaxf(acc[m][n][r] + bb, 0.f);
          ps[n] += t;
          qs[n] += t * t;
          y[(size_t)gr * 256 + c] = f2bf(t);
        }
      }
    }
  }
#pragma unroll
  for (int n = 0; n < 4; ++n) {
    ps[n] += __shfl_xor(ps[n], 16, 64);
    ps[n] += __shfl_xor(ps[n], 32, 64);
    qs[n] += __shfl_xor(qs[n], 16, 64);
    qs[n] += __shfl_xor(qs[n], 32, 64);
    if (lk == 0) {
      atomicAdd(&csum[wc * 64 + n * 16 + l16], ps[n]);
      atomicAdd(&csq[wc * 64 + n * 16 + l16], qs[n]);
    }
  }
  __syncthreads();
  for (int i = tid; i < 256; i += 512) {
    atomicAdd(&colsum[i], csum[i]);
    atomicAdd(&colsq[i], csq[i]);
  }
}

// ---------------------------------------------------------------------------
// K7: BN fold -> W2T[o][h] bf16 (o padded to 192), b2[o] f32
// ---------------------------------------------------------------------------
__global__ __launch_bounds__(256) void k_finalize(
    const float* __restrict__ colsum, const float* __restrict__ colsq,
    const float* __restrict__ gamma, const float* __restrict__ beta,
    const float* __restrict__ fcW, const float* __restrict__ fcb,
    unsigned short* __restrict__ W2T, float* __restrict__ b2) {
  const float invN = 1.0f / (float)N_NODES;
  if (blockIdx.x < 192) {
    int o = blockIdx.x, h = threadIdx.x;
    unsigned short v = 0;
    if (o < OUT_F) {
      float mu = colsum[h] * invN;
      float var = colsq[h] * invN - mu * mu;
      float rs = rsqrtf(var + BN_EPS) * gamma[h];
      v = f2bf(fcW[(size_t)h * OUT_F + o] * rs);
    }
    W2T[(size_t)o * 256 + h] = v;
  } else if (threadIdx.x < OUT_F) {
    int o = threadIdx.x;
    float acc = fcb[o];
    for (int h = 0; h < HID_F; ++h) {
      float mu = colsum[h] * invN;
      float var = colsq[h] * invN - mu * mu;
      float rs = rsqrtf(var + BN_EPS) * gamma[h];
      acc += (beta[h] - mu * rs) * fcW[(size_t)h * OUT_F + o];
    }
    b2[o] = acc;
  }
}

// ---------------------------------------------------------------------------
// K8: GEMM2 (MFMA bf16): out = y @ W2 + b2. Tile 128x192, BK=64, 8 waves.
// ---------------------------------------------------------------------------
__global__ __launch_bounds__(512) void k_gemm2(
    const unsigned short* __restrict__ y, const unsigned short* __restrict__ W2T,
    const float* __restrict__ b2, float* __restrict__ out) {
  __shared__ short As[128 * 72];
  __shared__ short Bs[192 * 72];

  const int tid = threadIdx.x;
  const int lane = tid & 63;
  const int wid = tid >> 6;
  const int wr = wid >> 2, wc = wid & 3;
  const int l16 = lane & 15, lk = lane >> 4;
  const int row0 = blockIdx.x * 128;

  const int sr = tid >> 3;
  const int sc = (tid & 7) * 8;

  f32x4 acc[4][3];
#pragma unroll
  for (int m = 0; m < 4; ++m)
#pragma unroll
    for (int n = 0; n < 3; ++n) acc[m][n] = (f32x4){0.f, 0.f, 0.f, 0.f};

  for (int ks = 0; ks < 4; ++ks) {
    const int k0 = ks * 64;
#pragma unroll
    for (int p = 0; p < 2; ++p) {
      int r = p * 64 + sr;
      int gr = row0 + r;
      bf16x8 v = {};
      if (gr < N_NODES)
        v = *reinterpret_cast<const bf16x8*>(y + (size_t)gr * 256 + k0 + sc);
      *reinterpret_cast<bf16x8*>(&As[r * 72 + sc]) = v;
    }
#pragma unroll
    for (int p = 0; p < 3; ++p) {
      int c = p * 64 + sr;
      bf16x8 v = *reinterpret_cast<const bf16x8*>(
          W2T + (size_t)c * 256 + k0 + sc);
      *reinterpret_cast<bf16x8*>(&Bs[c * 72 + sc]) = v;
    }
    __syncthreads();

#pragma unroll
    for (int kk = 0; kk < 2; ++kk) {
      bf16x8 af[4], bfr[3];
#pragma unroll
      for (int m = 0; m < 4; ++m)
        af[m] = *reinterpret_cast<const bf16x8*>(
            &As[(wr * 64 + m * 16 + l16) * 72 + kk * 32 + lk * 8]);
#pragma unroll
      for (int n = 0; n < 3; ++n)
        bfr[n] = *reinterpret_cast<const bf16x8*>(
            &Bs[(wc * 48 + n * 16 + l16) * 72 + kk * 32 + lk * 8]);
#pragma unroll
      for (int m = 0; m < 4; ++m)
#pragma unroll
        for (int n = 0; n < 3; ++n)
          acc[m][n] = __builtin_amdgcn_mfma_f32_16x16x32_bf16(
              af[m], bfr[n], acc[m][n], 0, 0, 0);
    }
    __syncthreads();
  }

#pragma unroll
  for (int n = 0; n < 3; ++n) {
    const int c = wc * 48 + n * 16 + l16;
    if (c < OUT_F) {
      const float bb = b2[c];
#pragma unroll
      for (int m = 0; m < 4; ++m) {
        const int rbase = row0 + wr * 64 + m * 16 + lk * 4;
#pragma unroll
        for (int r = 0; r < 4; ++r) {
          int gr = rbase + r;
          if (gr < N_NODES)
            out[(size_t)gr * OUT_F + c] = acc[m][n][r] + bb;
        }
      }
    }
  }
}

// ---------------------------------------------------------------------------
extern "C" void kernel_launch(void* const* d_in, const int* in_sizes, int n_in,
                              void* d_out, int out_size, void* d_ws,
                              size_t ws_size, hipStream_t stream) {
  const float* feat   = (const float*)d_in[0];
  const int*   src    = (const int*)d_in[1];
  const int*   dst    = (const int*)d_in[2];
  const float* ew     = (const float*)d_in[3];
  const float* Wself  = (const float*)d_in[4];
  const float* Wneigh = (const float*)d_in[5];
  const float* bias   = (const float*)d_in[6];
  const float* gamma  = (const float*)d_in[7];
  const float* beta   = (const float*)d_in[8];
  const float* fcW    = (const float*)d_in[9];
  const float* fcb    = (const float*)d_in[10];
  float* out = (float*)d_out;

  char* ws = (char*)d_ws;
  // layout (bytes):
  //   [0,        400,000)   cursor  N i32            (zeroed)
  //   [400,000,  401,024)   colsum  256 f32          (zeroed)
  //   [401,024,  402,048)   colsq   256 f32          (zeroed)
  //   [402,048,  802,052)   offs    (N+1) i32
  //   [802,304,  802,696)   totals  98 i32
  //   [802,816,  803,208)   bases   98 i32
  //   [803,328,  7,203,328) pairs   E u32
  //   [7,203,328, 58,403,328) A1    N*256 bf16 (feat | neigh)
  //   [58,403,328,58,534,400) W1T   256*256 bf16
  //   [58,534,400,58,632,704) W2T   192*256 bf16
  //   [58,632,704,58,633,344) b2    160 f32
  //   [58,633,344,109,833,344) y    N*256 bf16
  int*            cursor = (int*)(ws + 0);
  float*          colsum = (float*)(ws + 400000);
  float*          colsq  = (float*)(ws + 401024);
  int*            offs   = (int*)(ws + 402048);
  int*            totals = (int*)(ws + 802304);
  int*            bases  = (int*)(ws + 802816);
  unsigned*       pairs  = (unsigned*)(ws + 803328);
  unsigned*       A1u    = (unsigned*)(ws + 7203328);
  unsigned short* A1     = (unsigned short*)(ws + 7203328);
  unsigned short* W1T    = (unsigned short*)(ws + 58403328);
  unsigned short* W2T    = (unsigned short*)(ws + 58534400);
  float*          b2     = (float*)(ws + 58632704);
  unsigned short* y      = (unsigned short*)(ws + 58633344);

  hipMemsetAsync(ws, 0, 402048, stream);

  dim3 b256(256);
  k_convert<<<dim3((N_NODES * IN_F / 8 + 255) / 256), b256, 0, stream>>>(
      feat, A1u);
  k_prepw<<<dim3(256), b256, 0, stream>>>(Wself, Wneigh, W1T);
  k_hist<<<dim3(NCHUNK * 8), b256, 0, stream>>>(dst, cursor);
  k_scan1<<<dim3(SCHUNK), dim3(1024), 0, stream>>>(cursor, offs, totals);
  k_scan2<<<dim3(1), dim3(128), 0, stream>>>(totals, bases);
  k_scan3<<<dim3((N_NODES + 255) / 256), b256, 0, stream>>>(
      offs, cursor, bases);
  k_place<<<dim3(NCHUNK * 8), b256, 0, stream>>>(
      src, dst, ew, cursor, pairs);
  k_gather<<<dim3((N_NODES + 3) / 4), b256, 0, stream>>>(offs, pairs, A1u);
  k_gemm1<<<dim3((N_NODES + 127) / 128), dim3(512), 0, stream>>>(
      A1, W1T, bias, y, colsum, colsq);
  k_finalize<<<dim3(193), b256, 0, stream>>>(
      colsum, colsq, gamma, beta, fcW, fcb, W2T, b2);
  k_gemm2<<<dim3((N_NODES + 127) / 128), dim3(512), 0, stream>>>(
      y, W2T, b2, out);
}